// Round 1
// baseline (197.078 us; speedup 1.0000x reference)
//
#include <hip/hip_runtime.h>
#include <math.h>

// B=32 graphs, N=1024 nodes, D=128 in-dim, C=64 out-dim, K=16.
#define OUT_ELEMS 2097152   // 32768*64
#define EDGE_ELEMS 524288   // 32*1024*16

__device__ __forceinline__ unsigned int rotl32(unsigned int x, int r){
  return (x << r) | (x >> (32 - r));
}

// JAX partitionable threefry, key (0,1): counter = (0, e); out = o0 ^ o1.
__device__ __forceinline__ unsigned int tf_bits_part(unsigned int e){
  unsigned int x0 = 0u, x1 = e;
  const unsigned int ks1 = 1u;
  const unsigned int ks2 = 0x1BD11BDBu;
  x1 += ks1;
#define TFR(r) { x0 += x1; x1 = rotl32(x1, r); x1 ^= x0; }
  TFR(13) TFR(15) TFR(26) TFR(6)
  x0 += ks1; x1 += ks2 + 1u;
  TFR(17) TFR(29) TFR(16) TFR(24)
  x0 += ks2; x1 += 0u + 2u;
  TFR(13) TFR(15) TFR(26) TFR(6)
  x0 += 0u;  x1 += ks1 + 3u;
  TFR(17) TFR(29) TFR(16) TFR(24)
  x0 += ks1; x1 += ks2 + 4u;
  TFR(13) TFR(15) TFR(26) TFR(6)
  x0 += ks2; x1 += 0u + 5u;
#undef TFR
  return x0 ^ x1;
}

// hardware f64 reciprocal + 2 Newton steps: rel err ~1e-16.
__device__ __forceinline__ double rcp64(double x){
  double r;
  asm("v_rcp_f64 %0, %1" : "=v"(r) : "v"(x));
  double e = fma(-x, r, 1.0); r = fma(r, e, r);
  e = fma(-x, r, 1.0); r = fma(r, e, r);
  return r;
}

// fast e^x for x in [-740, ~1]; rel err ~2e-11 (deg-9).
__device__ __forceinline__ double fast_exp(double x){
  double fn = __builtin_rint(x * 1.4426950408889634);
  int n = (int)fn;
  double r = fma(fn, -0.6931471803691238, x);
  r = fma(fn, -1.9082149292705877e-10, r);
  double p = 2.7557319223985893e-06;
  p = fma(r, p, 2.4801587301587302e-05);
  p = fma(r, p, 1.9841269841269841e-04);
  p = fma(r, p, 1.3888888888888889e-03);
  p = fma(r, p, 8.3333333333333333e-03);
  p = fma(r, p, 4.1666666666666664e-02);
  p = fma(r, p, 1.6666666666666666e-01);
  p = fma(r, p, 0.5);
  p = fma(r, p, 1.0);
  p = fma(r, p, 1.0);
  double scale = __longlong_as_double(((long long)(n + 1023)) << 52);
  return p * scale;
}

// fast ln(x), normal positive x; atanh form; abs err ~2e-11.
__device__ __forceinline__ double fast_log(double x){
  long long bx = __double_as_longlong(x);
  long long e = (bx >> 52) - 1023;
  double m = __longlong_as_double((bx & 0xFFFFFFFFFFFFFll) |
                                  0x3FF0000000000000ll);
  int big = m > 1.4142135623730951;
  m = big ? 0.5 * m : m;
  e += big;
  double s = (m - 1.0) * rcp64(m + 1.0);
  double s2 = s * s;
  double p = fma(s2, 2.0/11.0, 2.0/9.0);
  p = fma(s2, p, 2.0/7.0);
  p = fma(s2, p, 2.0/5.0);
  p = fma(s2, p, 2.0/3.0);
  double lm = fma(s * s2, p, 2.0 * s);
  return fma((double)e, 0.6931471805599453, lm);
}

// Exact f64 score of candidate jc. Accumulation order q=0..63 sequential —
// bit-identical to v5..v10. unroll 4: only 4 float4 loads in flight.
__device__ __forceinline__ unsigned long long score_cand(
    const float* __restrict__ og, const double* __restrict__ hrow,
    unsigned int jc, unsigned int base, double Td, bool act){
  const float4* cp4 = (const float4*)(og + ((size_t)jc << 6));
  double acc = 0.0;
  #pragma unroll 4
  for (int ch = 0; ch < 16; ++ch){
    float4 cf = cp4[ch];
    double d0 = hrow[(ch << 2) + 0] - (double)cf.x;
    double d1 = hrow[(ch << 2) + 1] - (double)cf.y;
    double d2 = hrow[(ch << 2) + 2] - (double)cf.z;
    double d3 = hrow[(ch << 2) + 3] - (double)cf.w;
    acc = fma(d0, d0, acc);
    acc = fma(d1, d1, acc);
    acc = fma(d2, d2, acc);
    acc = fma(d3, d3, acc);
  }
  if (!act) return 0ull;
  double sgm = fast_exp(-Td * acc);
  unsigned int bits = tf_bits_part(base | jc);
  float f = __uint_as_float(0x3f800000u | (bits >> 9)) - 1.0f;
  double u = (f > 0.0f) ? (double)f : 1.1754943508222875e-38;
  double w = -fast_log(u);
  double z = -fast_log(w);
  double sc = sgm + z;
  unsigned long long kb = (unsigned long long)__double_as_longlong(sc);
  kb ^= (unsigned long long)(((long long)kb) >> 63) | 0x8000000000000000ull;
  return (kb & ~1023ull) | (unsigned long long)(1023u - jc);
}

// Full descending bitonic sort of u64 keys across 64 lanes.
__device__ __forceinline__ unsigned long long bitonic64_desc(
    unsigned long long key, int lane){
  #pragma unroll
  for (int k = 2; k <= 64; k <<= 1){
    #pragma unroll
    for (int j = k >> 1; j; j >>= 1){
      unsigned long long o = __shfl_xor(key, j, 64);
      bool keep_hi = ((lane & k) == 0) == ((lane & j) == 0);
      key = (keep_hi == (o > key)) ? o : key;
    }
  }
  return key;
}

// Full descending bitonic sort of u32 keys across 64 lanes.
__device__ __forceinline__ unsigned int bitonic32_desc(
    unsigned int key, int lane){
  #pragma unroll
  for (int k = 2; k <= 64; k <<= 1){
    #pragma unroll
    for (int j = k >> 1; j; j >>= 1){
      unsigned int o = __shfl_xor(key, j, 64);
      bool keep_hi = ((lane & k) == 0) == ((lane & j) == 0);
      key = (keep_hi == (o > key)) ? o : key;
    }
  }
  return key;
}

// ---------------- encoder ----------------
// v11: no LDS. v10 staged x as f64 in LDS and re-read 1 MB/wave through the
// LDS return path (broadcast ds_read_b128 still moves 16B x 64 lanes) ->
// LDS-BW bound (~70 us). The x row operand is wave-uniform: fetch it through
// the SCALAR path instead. Each wave owns 8 rows (readfirstlane makes the
// row base provably uniform -> s_load_dwordx4), lane = output column c.
// Per k: 1 coalesced W dword load (L1-resident) + 9 cvt + 8 v_fma_f64.
// fma order per (row,c) is k=0..127 ascending with exact f32->f64 cvts:
// bit-identical out vs v10.
__global__ __launch_bounds__(256) void encoder_v11(
    const float* __restrict__ x, const float* __restrict__ W,
    const float* __restrict__ b, float* __restrict__ out){
  const int tid = threadIdx.x;
  const int wu  = __builtin_amdgcn_readfirstlane(tid >> 6);  // wave id (SGPR)
  const int c   = tid & 63;
  const size_t r0 = ((size_t)blockIdx.x << 5) + ((size_t)wu << 3);
  const float* __restrict__ xr = x + (r0 << 7);   // 8 rows x 128, uniform

  double acc[8];
  const double bc = (double)b[c];
  #pragma unroll
  for (int i = 0; i < 8; ++i) acc[i] = bc;

  #pragma unroll 4
  for (int k = 0; k < 128; ++k){
    const double wk = (double)W[(k << 6) + c];
    #pragma unroll
    for (int i = 0; i < 8; ++i)
      acc[i] = fma((double)xr[((size_t)i << 7) + k], wk, acc[i]);
  }

  #pragma unroll
  for (int i = 0; i < 8; ++i)
    out[((r0 + i) << 6) + c] = (float)acc[i];
}

// ---------------- edges ----------------
// Unchanged from v10 (proven: ~118.5 us, VGPR 28, VALUBusy 86%).
__global__ __launch_bounds__(256, 8) void edges_v11(
    const float* __restrict__ out32, const float* __restrict__ temp,
    float* __restrict__ rows_out, float* __restrict__ cols_out){
  __shared__ double hid[4][64];         // 2 KB
  __shared__ unsigned int cl[4][128];   // 2 KB
  const int tid = threadIdx.x, wave = tid >> 6, lane = tid & 63;
  const int gb = blockIdx.x >> 8;
  const int i0 = (blockIdx.x & 255) << 2;
  const int r  = i0 + wave;
  const float* __restrict__ og = out32 + ((size_t)gb << 16);

  hid[wave][lane] = (double)og[((size_t)r << 6) + lane];

  const unsigned int base = ((unsigned int)gb << 20) | ((unsigned int)r << 10);

  // Phase 1: bits for j = m*64 + lane, with running per-lane max
  unsigned int v[16];
  unsigned int pmax = 0u;
  #pragma unroll
  for (int m = 0; m < 16; ++m){
    const unsigned int j = (unsigned int)(m << 6) + (unsigned int)lane;
    unsigned int bits = tf_bits_part(base | j);
    v[m] = (bits & ~1023u) | (1023u - j);   // low 10 bits don't feed u
    pmax = (v[m] > pmax) ? v[m] : pmax;
  }

  // Phase 2: 16th-largest lane-max (conservative surrogate for b16)
  unsigned int sorted = bitonic32_desc(pmax, lane);
  unsigned int b16p = __shfl(sorted, 15, 64);

  // conservative cut: keep j iff z_j >= z(b16') - 1.001  (score <= z + 1)
  float u16 = __uint_as_float(0x3f800000u | (b16p >> 9)) - 1.0f;
  float z16 = -__logf(-__logf(u16));
  float uc  = __expf(-__expf(-(z16 - 1.001f)));
  unsigned int cp = ((__float_as_uint(1.0f + uc) & 0x7FFFFFu) << 9) & ~1023u;

  // Phase 3: compaction of all survivors (>=16 guaranteed since cut < b16')
  int cnt = 0;
  #pragma unroll
  for (int m = 0; m < 16; ++m) cnt += (v[m] >= cp) ? 1 : 0;
  int s = cnt;
  #pragma unroll
  for (int off = 1; off < 64; off <<= 1){
    int o = __shfl_up(s, off, 64);
    s += (lane >= off) ? o : 0;
  }
  int nc = __shfl(s, 63, 64);
  nc = (nc > 128) ? 128 : nc;
  int slot = s - cnt;
  #pragma unroll
  for (int m = 0; m < 16; ++m){
    if (v[m] >= cp && slot < 128){
      cl[wave][slot] = 1023u - (v[m] & 1023u);
      ++slot;
    }
  }

  // Phase 4: exact scoring + sort
  const double Td = (double)temp[0];
  const bool act1 = (lane < nc);
  unsigned int jc1 = act1 ? cl[wave][lane] : 0u;
  unsigned long long key = score_cand(og, hid[wave], jc1, base, Td, act1);
  key = bitonic64_desc(key, lane);

  if (nc > 64){
    const int idx2 = 64 + lane;
    const bool act2 = (idx2 < nc);
    unsigned int jc2 = act2 ? cl[wave][idx2] : 0u;
    unsigned long long k2 = score_cand(og, hid[wave], jc2, base, Td, act2);
    k2 = bitonic64_desc(k2, lane);
    unsigned long long kr = __shfl(k2, 63 - lane, 64);
    key = (kr > key) ? kr : key;          // elementwise top-64 (bitonic)
    #pragma unroll
    for (int j = 32; j; j >>= 1){         // descending clean
      unsigned long long o = __shfl_xor(key, j, 64);
      bool left = (lane & j) == 0;
      bool take = left ? (o > key) : (o < key);
      key = take ? o : key;
    }
  }

  const int grow = (gb << 10) + r;
  if (lane < 16){
    rows_out[((size_t)grow << 4) + lane] = (float)grow;
    cols_out[((size_t)grow << 4) + lane] =
        (float)((gb << 10) + (1023 - (int)(key & 1023ull)));
  }
}

extern "C" void kernel_launch(void* const* d_in, const int* in_sizes, int n_in,
                              void* d_out, int out_size, void* d_ws, size_t ws_size,
                              hipStream_t stream){
  const float* x = (const float*)d_in[0];
  const float* W = (const float*)d_in[1];
  const float* b = (const float*)d_in[2];
  const float* T = (const float*)d_in[3];
  float* out      = (float*)d_out;
  float* rows_out = out + OUT_ELEMS;
  float* cols_out = rows_out + EDGE_ELEMS;

  encoder_v11<<<1024, 256, 0, stream>>>(x, W, b, out);
  edges_v11<<<8192, 256, 0, stream>>>(out, T, rows_out, cols_out);
}